// Round 1
// baseline (1071.270 us; speedup 1.0000x reference)
//
#include <hip/hip_runtime.h>
#include <stdint.h>

// Problem: y[b,s,o] = sum_d x[b,s,d] * (wq[o,d]*scale) + bias[o]
// M = B*S = 16384, N = D_OUT = 4096, K = D_IN = 4096. fp32 out.
constexpr int M = 16384;
constexpr int N = 4096;
constexpr int K = 4096;
constexpr int BM = 128, BN = 128, BK = 32;

typedef __attribute__((ext_vector_type(8))) __bf16 bf16x8;
typedef __attribute__((ext_vector_type(4))) float f32x4;

// RNE f32 -> bf16 (bit-level; exact for small ints, matches np rounding well
// within the 5.1 absmax budget)
__device__ __forceinline__ unsigned short f32_bf16(float f) {
    union { float f; unsigned int u; } v; v.f = f;
    unsigned int r = v.u + 0x7FFFu + ((v.u >> 16) & 1u);
    return (unsigned short)(r >> 16);
}

// x: fp32 -> bf16, 4 elems/thread, vectorized
__global__ void cvt_x_kernel(const float* __restrict__ x,
                             unsigned short* __restrict__ o) {
    const int i = blockIdx.x * blockDim.x + threadIdx.x;
    float4 v = ((const float4*)x)[i];
    ushort4 r;
    r.x = f32_bf16(v.x); r.y = f32_bf16(v.y);
    r.z = f32_bf16(v.z); r.w = f32_bf16(v.w);
    ((ushort4*)o)[i] = r;
}

// wq: int32 [0,127] -> bf16 (exact)
__global__ void cvt_w_kernel(const int* __restrict__ q,
                             unsigned short* __restrict__ o) {
    const int i = blockIdx.x * blockDim.x + threadIdx.x;
    int4 v = ((const int4*)q)[i];
    ushort4 r;
    r.x = f32_bf16((float)v.x); r.y = f32_bf16((float)v.y);
    r.z = f32_bf16((float)v.z); r.w = f32_bf16((float)v.w);
    ((ushort4*)o)[i] = r;
}

// m97-structure GEMM: C[m,n] = sum_k A[m,k]*B[n,k], A=[M,K] bf16, B=[N,K] bf16
// 128x128 tile / block (256 thr = 4 waves, 2x2 wave grid, 64x64 per wave,
// 4x4 MFMA 16x16x32 tiles). global_load_lds width=16 staging, BK=32.
__global__ __launch_bounds__(256) void gemm_bt_kernel(
    const unsigned short* __restrict__ A,
    const unsigned short* __restrict__ Bq,
    const float* __restrict__ scale,
    const float* __restrict__ bias,
    float* __restrict__ C) {
    __shared__ unsigned short As[BM * BK];  // 8 KB, natural layout (no pad:
    __shared__ unsigned short Bs[BN * BK];  // global_load_lds needs lane-order)

    const int t    = threadIdx.x;
    const int lane = t & 63;
    const int wave = t >> 6;
    const int wr   = wave >> 1;      // wave row (0/1) -> 64-row half
    const int wc   = wave & 1;       // wave col (0/1) -> 64-col half
    const int r16  = lane & 15;
    const int quad = lane >> 4;

    const int mBase = blockIdx.y * BM;
    const int nBase = blockIdx.x * BN;

    // staging: thread t covers tile row t>>2, col segment (t&3)*8 (16 B)
    const int srow = t >> 2;
    const int scol = (t & 3) * 8;
    const unsigned short* Ag0 = A  + (size_t)(mBase + srow)      * K + scol;
    const unsigned short* Ag1 = A  + (size_t)(mBase + 64 + srow) * K + scol;
    const unsigned short* Bg0 = Bq + (size_t)(nBase + srow)      * K + scol;
    const unsigned short* Bg1 = Bq + (size_t)(nBase + 64 + srow) * K + scol;

    typedef __attribute__((address_space(3))) unsigned short* lds_p;
    typedef const __attribute__((address_space(1))) unsigned short* g_p;

    f32x4 acc[4][4];
    const f32x4 zero = {0.0f, 0.0f, 0.0f, 0.0f};
#pragma unroll
    for (int i = 0; i < 4; i++)
#pragma unroll
        for (int j = 0; j < 4; j++) acc[i][j] = zero;

    for (int k0 = 0; k0 < K; k0 += BK) {
        // global -> LDS direct (HW dest = wave-uniform base + lane*16)
        __builtin_amdgcn_global_load_lds((g_p)(Ag0 + k0), (lds_p)(As + t * 8),        16, 0, 0);
        __builtin_amdgcn_global_load_lds((g_p)(Ag1 + k0), (lds_p)(As + 2048 + t * 8), 16, 0, 0);
        __builtin_amdgcn_global_load_lds((g_p)(Bg0 + k0), (lds_p)(Bs + t * 8),        16, 0, 0);
        __builtin_amdgcn_global_load_lds((g_p)(Bg1 + k0), (lds_p)(Bs + 2048 + t * 8), 16, 0, 0);
        __syncthreads();  // compiler emits vmcnt(0) drain before s_barrier

        bf16x8 av[4], bv[4];
#pragma unroll
        for (int mi = 0; mi < 4; mi++)
            av[mi] = *(const bf16x8*)&As[(wr * 64 + mi * 16 + r16) * BK + quad * 8];
#pragma unroll
        for (int ni = 0; ni < 4; ni++)
            bv[ni] = *(const bf16x8*)&Bs[(wc * 64 + ni * 16 + r16) * BK + quad * 8];
#pragma unroll
        for (int mi = 0; mi < 4; mi++)
#pragma unroll
            for (int ni = 0; ni < 4; ni++)
                acc[mi][ni] = __builtin_amdgcn_mfma_f32_16x16x32_bf16(
                    av[mi], bv[ni], acc[mi][ni], 0, 0, 0);
        __syncthreads();  // protect LDS before next stage overwrites
    }

    // epilogue: C = acc*scale + bias. C/D layout: col=lane&15, row=quad*4+reg
    const float scl = scale[0];
    float bvals[4];
#pragma unroll
    for (int ni = 0; ni < 4; ni++)
        bvals[ni] = bias[nBase + wc * 64 + ni * 16 + r16];

#pragma unroll
    for (int mi = 0; mi < 4; mi++) {
#pragma unroll
        for (int ni = 0; ni < 4; ni++) {
            const int col = nBase + wc * 64 + ni * 16 + r16;
#pragma unroll
            for (int r = 0; r < 4; r++) {
                const int row = mBase + wr * 64 + mi * 16 + quad * 4 + r;
                C[(size_t)row * N + col] = acc[mi][ni][r] * scl + bvals[ni];
            }
        }
    }
}

extern "C" void kernel_launch(void* const* d_in, const int* in_sizes, int n_in,
                              void* d_out, int out_size, void* d_ws, size_t ws_size,
                              hipStream_t stream) {
    const float* x     = (const float*)d_in[0];
    const int*   wq    = (const int*)d_in[1];
    const float* scale = (const float*)d_in[2];
    const float* bias  = (const float*)d_in[3];
    float*       out   = (float*)d_out;

    // workspace: x_bf16 [M*K] then w_bf16 [N*K]  (needs 160 MB)
    unsigned short* xb = (unsigned short*)d_ws;
    unsigned short* wb = xb + (size_t)M * K;

    cvt_x_kernel<<<(M * (size_t)K) / 4 / 256, 256, 0, stream>>>(x, xb);
    cvt_w_kernel<<<(N * (size_t)K) / 4 / 256, 256, 0, stream>>>(wq, wb);

    dim3 grid(N / BN, M / BM);  // (32, 128)
    gemm_bt_kernel<<<grid, 256, 0, stream>>>(xb, wb, scale, bias, out);
}

// Round 2
// 872.350 us; speedup vs baseline: 1.2280x; 1.2280x over previous
//
#include <hip/hip_runtime.h>
#include <stdint.h>

// y[m,o] = sum_d x[m,d] * (wq[o,d]*scale) + bias[o]
// M = B*S = 16384, N = D_OUT = 4096, K = D_IN = 4096. fp32 out.
// Path: per-row i8 quant of x (only error source; wq is EXACT in i8),
// i8 MFMA (2x bf16 rate, half staging bytes), exact i32 accumulate,
// fp32 dequant epilogue: y = acc * (row_step * scale) + bias.
constexpr int M = 16384;
constexpr int N = 4096;
constexpr int K = 4096;
constexpr int BM = 128, BN = 128, BK = 64;

typedef __attribute__((ext_vector_type(4))) int i32x4;

// x: fp32 -> i8 with per-row scale. One block per row (K=4096, 256 thr x 16).
__global__ __launch_bounds__(256) void quant_x_kernel(
    const float* __restrict__ x, signed char* __restrict__ o,
    float* __restrict__ row_step) {
    const int row = blockIdx.x;
    const int t = threadIdx.x;
    const float* xr = x + (size_t)row * K;
    float4 v[4];
#pragma unroll
    for (int i = 0; i < 4; i++) v[i] = ((const float4*)xr)[t + 256 * i];

    float amax = 0.f;
#pragma unroll
    for (int i = 0; i < 4; i++)
        amax = fmaxf(amax,
               fmaxf(fmaxf(fabsf(v[i].x), fabsf(v[i].y)),
                     fmaxf(fabsf(v[i].z), fabsf(v[i].w))));
#pragma unroll
    for (int off = 32; off > 0; off >>= 1)
        amax = fmaxf(amax, __shfl_xor(amax, off, 64));
    __shared__ float wmax[4];
    if ((t & 63) == 0) wmax[t >> 6] = amax;
    __syncthreads();
    amax = fmaxf(fmaxf(wmax[0], wmax[1]), fmaxf(wmax[2], wmax[3]));

    const float inv = (amax > 0.f) ? 127.0f / amax : 0.f;
    if (t == 0) row_step[row] = (amax > 0.f) ? amax / 127.0f : 0.f;

    signed char* orow = o + (size_t)row * K;
#pragma unroll
    for (int i = 0; i < 4; i++) {
        char4 r;
        r.x = (signed char)__float2int_rn(v[i].x * inv);
        r.y = (signed char)__float2int_rn(v[i].y * inv);
        r.z = (signed char)__float2int_rn(v[i].z * inv);
        r.w = (signed char)__float2int_rn(v[i].w * inv);
        ((char4*)orow)[t + 256 * i] = r;
    }
}

// wq: int32 [0,127] -> i8 (EXACT, no scaling needed beyond the tensor scale)
__global__ void quant_w_kernel(const int* __restrict__ q,
                               signed char* __restrict__ o) {
    const int i = blockIdx.x * blockDim.x + threadIdx.x;
    int4 v = ((const int4*)q)[i];
    char4 r;
    r.x = (signed char)v.x; r.y = (signed char)v.y;
    r.z = (signed char)v.z; r.w = (signed char)v.w;
    ((char4*)o)[i] = r;
}

// i8 GEMM, m97 structure: C[m,n] = sum_k A[m,k]*B[n,k] (i32 acc).
// 128x128 tile / block (4 waves 2x2, 64x64/wave, 4x4 MFMA 16x16x64 i8),
// BK=64 (one MFMA-K per stage), global_load_lds width=16 staging.
__global__ __launch_bounds__(256) void gemm_i8_kernel(
    const signed char* __restrict__ A,
    const signed char* __restrict__ B,
    const float* __restrict__ row_step,
    const float* __restrict__ scale,
    const float* __restrict__ bias,
    float* __restrict__ C) {
    __shared__ signed char As[BM * BK];  // 8 KB, lane-order layout
    __shared__ signed char Bs[BN * BK];  // (global_load_lds: base + lane*16)

    const int t    = threadIdx.x;
    const int lane = t & 63;
    const int wave = t >> 6;
    const int wr   = wave >> 1;
    const int wc   = wave & 1;
    const int r16  = lane & 15;
    const int quad = lane >> 4;

    const int mBase = blockIdx.y * BM;
    const int nBase = blockIdx.x * BN;

    // staging: thread t covers tile row t>>2, byte segment (t&3)*16
    const int srow = t >> 2;
    const int scol = (t & 3) * 16;
    const signed char* Ag0 = A + (size_t)(mBase + srow)      * K + scol;
    const signed char* Ag1 = A + (size_t)(mBase + 64 + srow) * K + scol;
    const signed char* Bg0 = B + (size_t)(nBase + srow)      * K + scol;
    const signed char* Bg1 = B + (size_t)(nBase + 64 + srow) * K + scol;

    typedef __attribute__((address_space(3))) signed char* lds_p;
    typedef const __attribute__((address_space(1))) signed char* g_p;

    i32x4 acc[4][4];
    const i32x4 zero = {0, 0, 0, 0};
#pragma unroll
    for (int i = 0; i < 4; i++)
#pragma unroll
        for (int j = 0; j < 4; j++) acc[i][j] = zero;

    for (int k0 = 0; k0 < K; k0 += BK) {
        __builtin_amdgcn_global_load_lds((g_p)(Ag0 + k0), (lds_p)(As + t * 16),        16, 0, 0);
        __builtin_amdgcn_global_load_lds((g_p)(Ag1 + k0), (lds_p)(As + 4096 + t * 16), 16, 0, 0);
        __builtin_amdgcn_global_load_lds((g_p)(Bg0 + k0), (lds_p)(Bs + t * 16),        16, 0, 0);
        __builtin_amdgcn_global_load_lds((g_p)(Bg1 + k0), (lds_p)(Bs + 4096 + t * 16), 16, 0, 0);
        __syncthreads();

        // A fragment (16x16x64 i8): lane holds A[m=lane&15][k=quad*16 + j], 16B
        i32x4 av[4], bv[4];
#pragma unroll
        for (int mi = 0; mi < 4; mi++)
            av[mi] = *(const i32x4*)&As[(wr * 64 + mi * 16 + r16) * BK + quad * 16];
#pragma unroll
        for (int ni = 0; ni < 4; ni++)
            bv[ni] = *(const i32x4*)&Bs[(wc * 64 + ni * 16 + r16) * BK + quad * 16];
#pragma unroll
        for (int mi = 0; mi < 4; mi++)
#pragma unroll
            for (int ni = 0; ni < 4; ni++)
                acc[mi][ni] = __builtin_amdgcn_mfma_i32_16x16x64_i8(
                    av[mi], bv[ni], acc[mi][ni], 0, 0, 0);
        __syncthreads();
    }

    // epilogue: y = acc * (row_step[row]*scale) + bias[col]
    // C/D layout (shape-determined): col=lane&15, row=quad*4+reg
    const float s0 = scale[0];
    float bvals[4];
#pragma unroll
    for (int ni = 0; ni < 4; ni++)
        bvals[ni] = bias[nBase + wc * 64 + ni * 16 + r16];
    float rsv[4][4];
#pragma unroll
    for (int mi = 0; mi < 4; mi++)
#pragma unroll
        for (int r = 0; r < 4; r++)
            rsv[mi][r] = row_step[mBase + wr * 64 + mi * 16 + quad * 4 + r] * s0;

#pragma unroll
    for (int mi = 0; mi < 4; mi++) {
#pragma unroll
        for (int ni = 0; ni < 4; ni++) {
            const int col = nBase + wc * 64 + ni * 16 + r16;
#pragma unroll
            for (int r = 0; r < 4; r++) {
                const int row = mBase + wr * 64 + mi * 16 + quad * 4 + r;
                C[(size_t)row * N + col] =
                    (float)acc[mi][ni][r] * rsv[mi][r] + bvals[ni];
            }
        }
    }
}

extern "C" void kernel_launch(void* const* d_in, const int* in_sizes, int n_in,
                              void* d_out, int out_size, void* d_ws, size_t ws_size,
                              hipStream_t stream) {
    const float* x     = (const float*)d_in[0];
    const int*   wq    = (const int*)d_in[1];
    const float* scale = (const float*)d_in[2];
    const float* bias  = (const float*)d_in[3];
    float*       out   = (float*)d_out;

    // ws layout: row_step [M f32] | x_i8 [M*K] | w_i8 [N*K]  (~80 MB)
    float*       rs = (float*)d_ws;
    signed char* xb = (signed char*)(rs + M);
    signed char* wb = xb + (size_t)M * K;

    quant_x_kernel<<<M, 256, 0, stream>>>(x, xb, rs);
    quant_w_kernel<<<((size_t)N * K / 4) / 256, 256, 0, stream>>>(wq, wb);

    dim3 grid(N / BN, M / BM);  // (32, 128)
    gemm_i8_kernel<<<grid, 256, 0, stream>>>(xb, wb, rs, scale, bias, out);
}